// Round 1
// baseline (117.177 us; speedup 1.0000x reference)
//
#include <hip/hip_runtime.h>

#define LAMBDA_COORD 5.0f
#define LAMBDA_NOOBJ 0.5f

constexpr int Bn = 64;       // batch
constexpr int An = 10647;    // anchors
constexpr int Cn = 9;        // classes
constexpr int Gn = 50;       // gt boxes
constexpr int PRED_ROW = 5 + Cn;  // 14 floats per anchor row
constexpr int S  = 16;            // anchor splits
constexpr int AC = (An + S - 1) / S;  // 666 anchors per split

// ws layout:
//   partials : Bn*Gn*S float2 (iou, idx-as-bits)   = 409600 B
//   bcepart  : Bn*S floats                          = 4096 B
//   per_img  : Bn floats                            = 256 B

__global__ __launch_bounds__(256) void yolo_k1(
    const float* __restrict__ pred,     // [B, A, 14]
    const float* __restrict__ bboxes,   // [B, G, 4]
    float2* __restrict__ partials,      // [B, G, S]
    float* __restrict__ bcepart)        // [B, S]
{
    const int s = blockIdx.x;
    const int b = blockIdx.y;
    const int a0 = s * AC;
    const int a1 = min(a0 + AC, An);
    const int n  = a1 - a0;

    __shared__ float4 sbox[AC];  // x1,y1,x2,y2
    __shared__ float  sap[AC];   // area_p
    __shared__ float  sred[4];

    const int tid  = threadIdx.x;
    const int wave = tid >> 6;
    const int lane = tid & 63;

    // ---- stage anchors into LDS, accumulate partial bce0 sum ----
    const float* prow = pred + (size_t)b * An * PRED_ROW;
    float bce = 0.0f;
    for (int i = tid; i < n; i += 256) {
        const float* p = prow + (size_t)(a0 + i) * PRED_ROW;
        float cx = p[0], cy = p[1], w = p[2], h = p[3], conf = p[4];
        float hw = 0.5f * w, hh = 0.5f * h;
        float x1 = cx - hw, x2 = cx + hw;
        float y1 = cy - hh, y2 = cy + hh;
        sbox[i] = make_float4(x1, y1, x2, y2);
        sap[i]  = (x2 - x1) * (y2 - y1);
        // bce0 = -max(log(1-conf), -100)
        bce -= fmaxf(__logf(1.0f - conf), -100.0f);
    }
    #pragma unroll
    for (int off = 32; off >= 1; off >>= 1) bce += __shfl_xor(bce, off, 64);
    if (lane == 0) sred[wave] = bce;
    __syncthreads();
    if (tid == 0) bcepart[b * S + s] = sred[0] + sred[1] + sred[2] + sred[3];

    // ---- each wave handles a strided subset of GTs ----
    const float* bb = bboxes + (size_t)b * Gn * 4;
    for (int g = wave; g < Gn; g += 4) {
        float b0 = bb[g * 4 + 0], b1 = bb[g * 4 + 1];
        float b2 = bb[g * 4 + 2], b3 = bb[g * 4 + 3];
        // reference arithmetic order: cx=(x1+x2)/2, w=x2-x1, corners = cx -/+ w/2
        float gcx = 0.5f * (b0 + b2), gcy = 0.5f * (b1 + b3);
        float gw = b2 - b0, gh = b3 - b1;
        float gx1 = gcx - gw * 0.5f, gx2 = gcx + gw * 0.5f;
        float gy1 = gcy - gh * 0.5f, gy2 = gcy + gh * 0.5f;
        float c1 = (gx2 - gx1) * (gy2 - gy1) + 1e-16f;  // area_g + eps

        float best = -1.0f;
        int   bidx = 0x7fffffff;
        for (int i = lane; i < n; i += 64) {
            float4 pb = sbox[i];
            float iw = fminf(pb.z, gx2) - fmaxf(pb.x, gx1);
            float ih = fminf(pb.w, gy2) - fmaxf(pb.y, gy1);
            iw = fmaxf(iw, 0.0f);
            ih = fmaxf(ih, 0.0f);
            float inter = iw * ih;
            float denom = (sap[i] + c1) - inter;
            float iou = inter * __builtin_amdgcn_rcpf(denom);
            if (iou > best) { best = iou; bidx = a0 + i; }  // strict >: first max wins
        }
        // wave argmax reduce (max iou, tie -> smaller index)
        #pragma unroll
        for (int off = 1; off < 64; off <<= 1) {
            float oi  = __shfl_xor(best, off, 64);
            int   oix = __shfl_xor(bidx, off, 64);
            if (oi > best || (oi == best && oix < bidx)) { best = oi; bidx = oix; }
        }
        if (lane == 0)
            partials[((size_t)b * Gn + g) * S + s] = make_float2(best, __int_as_float(bidx));
    }
}

__global__ __launch_bounds__(64) void yolo_k2(
    const float* __restrict__ pred,
    const float* __restrict__ bboxes,
    const int*  __restrict__ classes,   // [B, G]
    const float2* __restrict__ partials,
    const float* __restrict__ bcepart,
    float* __restrict__ per_img)        // [B]
{
    const int b = blockIdx.x;
    const int g = threadIdx.x;

    float tot0 = 0.0f;
    #pragma unroll
    for (int s = 0; s < S; ++s) tot0 += bcepart[b * S + s];

    float per_gt = 0.0f;
    int   validf = 0;
    if (g < Gn) {
        int cls = classes[b * Gn + g];
        validf = (cls != -1) ? 1 : 0;

        // fold the S partial argmax candidates
        const float2* pp = partials + ((size_t)b * Gn + g) * S;
        float best = -1.0f;
        int   bidx = 0x7fffffff;
        #pragma unroll
        for (int s = 0; s < S; ++s) {
            float2 c = pp[s];
            float ci = c.x;
            int   cx = __float_as_int(c.y);
            if (ci > best || (ci == best && cx < bidx)) { best = ci; bidx = cx; }
        }

        const float* p = pred + ((size_t)b * An + bidx) * PRED_ROW;
        float pcx = p[0], pcy = p[1], pw = p[2], ph = p[3], conf = p[4];

        const float* bb = bboxes + ((size_t)b * Gn + g) * 4;
        float b0 = bb[0], b1 = bb[1], b2 = bb[2], b3 = bb[3];
        float gcx = 0.5f * (b0 + b2), gcy = 0.5f * (b1 + b3);
        float gw = b2 - b0, gh = b3 - b1;

        float dx = pcx - gcx, dy = pcy - gcy, dw = pw - gw, dh = ph - gh;
        float coord = LAMBDA_COORD * (dx * dx + dy * dy + dw * dw + dh * dh);

        float conf_obj = -fmaxf(__logf(conf), -100.0f);

        float clsl = 0.0f;
        #pragma unroll
        for (int c = 0; c < Cn; ++c) {
            float pc = p[5 + c];
            float lp = fmaxf(__logf(pc), -100.0f);
            float ln = fmaxf(__logf(1.0f - pc), -100.0f);
            clsl -= (c == cls) ? lp : ln;
        }

        float bce0b = -fmaxf(__logf(1.0f - conf), -100.0f);
        float noobj = LAMBDA_NOOBJ * (tot0 - bce0b);

        per_gt = coord + conf_obj + clsl + noobj;
        if (!validf) per_gt = 0.0f;
    }

    float sum = per_gt;
    int   anyv = validf;
    #pragma unroll
    for (int off = 1; off < 64; off <<= 1) {
        sum  += __shfl_xor(sum, off, 64);
        anyv |= __shfl_xor(anyv, off, 64);
    }
    if (g == 0) per_img[b] = anyv ? sum : (LAMBDA_NOOBJ * tot0);
}

__global__ __launch_bounds__(64) void yolo_k3(
    const float* __restrict__ per_img, float* __restrict__ out)
{
    float v = per_img[threadIdx.x];  // Bn == 64 == one wave
    #pragma unroll
    for (int off = 1; off < 64; off <<= 1) v += __shfl_xor(v, off, 64);
    if (threadIdx.x == 0) out[0] = v * (1.0f / (float)Bn);
}

extern "C" void kernel_launch(void* const* d_in, const int* in_sizes, int n_in,
                              void* d_out, int out_size, void* d_ws, size_t ws_size,
                              hipStream_t stream) {
    const float* pred    = (const float*)d_in[0];
    const float* bboxes  = (const float*)d_in[1];
    const int*   classes = (const int*)d_in[2];
    float* out = (float*)d_out;

    char* ws = (char*)d_ws;
    float2* partials = (float2*)ws;
    float*  bcepart  = (float*)(ws + (size_t)Bn * Gn * S * sizeof(float2));
    float*  per_img  = (float*)(ws + (size_t)Bn * Gn * S * sizeof(float2)
                                   + (size_t)Bn * S * sizeof(float));

    yolo_k1<<<dim3(S, Bn), 256, 0, stream>>>(pred, bboxes, partials, bcepart);
    yolo_k2<<<Bn, 64, 0, stream>>>(pred, bboxes, classes, partials, bcepart, per_img);
    yolo_k3<<<1, 64, 0, stream>>>(per_img, out);
}

// Round 2
// 107.936 us; speedup vs baseline: 1.0856x; 1.0856x over previous
//
#include <hip/hip_runtime.h>

#define LAMBDA_COORD 5.0f
#define LAMBDA_NOOBJ 0.5f

constexpr int Bn = 64;       // batch
constexpr int An = 10647;    // anchors
constexpr int Cn = 9;        // classes
constexpr int Gn = 50;       // gt boxes
constexpr int PRED_ROW = 5 + Cn;        // 14 floats per anchor row
constexpr int S  = 16;                  // anchor splits
constexpr int AC = (An + S - 1) / S;    // 666 anchors per split
constexpr int GTW = 13;                 // GTs per wave (13+13+13+11 = 50)

// ws layout:
//   partials : Bn*Gn*S float2 (score, idx-as-bits)  = 409600 B
//   bcepart  : Bn*S floats                           = 4096 B
//   per_img  : Bn floats                             = 256 B

__global__ __launch_bounds__(256) void yolo_k1(
    const float* __restrict__ pred,     // [B, A, 14]
    const float* __restrict__ bboxes,   // [B, G, 4]
    float2* __restrict__ partials,      // [B, G, S]
    float* __restrict__ bcepart)        // [B, S]
{
    const int s = blockIdx.x;
    const int b = blockIdx.y;
    const int a0 = s * AC;
    const int n  = min(AC, An - a0);

    __shared__ float4 sbox[AC];  // x1,y1,x2,y2
    __shared__ float  sap[AC];   // area_p
    __shared__ float  sred[4];

    const int tid  = threadIdx.x;
    const int wave = tid >> 6;
    const int lane = tid & 63;

    // ---- stage anchors into LDS, accumulate partial bce0 sum ----
    const float* prow = pred + (size_t)b * An * PRED_ROW;
    float bce = 0.0f;
    for (int i = tid; i < n; i += 256) {
        const float* p = prow + (size_t)(a0 + i) * PRED_ROW;
        float cx = p[0], cy = p[1], w = p[2], h = p[3], conf = p[4];
        float hw = 0.5f * w, hh = 0.5f * h;
        float x1 = cx - hw, x2 = cx + hw;
        float y1 = cy - hh, y2 = cy + hh;
        sbox[i] = make_float4(x1, y1, x2, y2);
        sap[i]  = (x2 - x1) * (y2 - y1);
        bce -= fmaxf(__logf(1.0f - conf), -100.0f);   // bce0 = -max(log(1-conf),-100)
    }
    #pragma unroll
    for (int off = 32; off >= 1; off >>= 1) bce += __shfl_xor(bce, off, 64);
    if (lane == 0) sred[wave] = bce;

    // ---- per-wave GT tile into registers ----
    const int g0 = wave * GTW;
    const int ng = min(GTW, Gn - g0);   // 13,13,13,11

    float gx1[GTW], gy1[GTW], gx2[GTW], gy2[GTW], gc1[GTW];
    const float* bb = bboxes + (size_t)b * Gn * 4;
    #pragma unroll
    for (int j = 0; j < GTW; ++j) {
        int g = (j < ng) ? (g0 + j) : g0;    // pad tail with duplicate of first GT
        float b0 = bb[g * 4 + 0], b1 = bb[g * 4 + 1];
        float b2 = bb[g * 4 + 2], b3 = bb[g * 4 + 3];
        float gcx = 0.5f * (b0 + b2), gcy = 0.5f * (b1 + b3);
        float gw = b2 - b0, gh = b3 - b1;
        gx1[j] = gcx - gw * 0.5f; gx2[j] = gcx + gw * 0.5f;
        gy1[j] = gcy - gh * 0.5f; gy2[j] = gcy + gh * 0.5f;
        gc1[j] = (gx2[j] - gx1[j]) * (gy2[j] - gy1[j]) + 1e-16f;  // area_g + eps
    }

    float bn[GTW], bd[GTW];
    int   bidx[GTW];
    #pragma unroll
    for (int j = 0; j < GTW; ++j) { bn[j] = -1.0f; bd[j] = 1.0f; bidx[j] = 0; }

    __syncthreads();
    if (tid == 0) bcepart[b * S + s] = sred[0] + sred[1] + sred[2] + sred[3];

    // ---- main scan: each anchor read once per wave, 13 IoUs per read ----
    for (int base = 0; base < n; base += 64) {
        int i = base + lane;
        if (i < n) {
            float4 pb = sbox[i];
            float  ap = sap[i];
            int   idx = a0 + i;
            #pragma unroll
            for (int j = 0; j < GTW; ++j) {
                float iw = fminf(pb.z, gx2[j]) - fmaxf(pb.x, gx1[j]);
                float ih = fminf(pb.w, gy2[j]) - fmaxf(pb.y, gy1[j]);
                iw = fmaxf(iw, 0.0f);
                ih = fmaxf(ih, 0.0f);
                float inter = iw * ih;
                float apc   = ap + gc1[j];
                // argmax of inter/(ap+ag-inter) == argmax of inter/(ap+ag)
                // (monotone transform); compare fractions by cross-multiply.
                bool take = inter * bd[j] > bn[j] * apc;   // strict >: first max wins
                bn[j]   = take ? inter : bn[j];
                bd[j]   = take ? apc   : bd[j];
                bidx[j] = take ? idx   : bidx[j];
            }
        }
    }

    // ---- cross-lane argmax per GT, write partial ----
    #pragma unroll
    for (int j = 0; j < GTW; ++j) {
        if (j < ng) {
            float score = bn[j] * __builtin_amdgcn_rcpf(bd[j]);  // monotone in iou
            int   idx   = bidx[j];
            #pragma unroll
            for (int off = 1; off < 64; off <<= 1) {
                float os = __shfl_xor(score, off, 64);
                int   oi = __shfl_xor(idx, off, 64);
                if (os > score) { score = os; idx = oi; }
            }
            if (lane == 0)
                partials[((size_t)b * Gn + g0 + j) * S + s] =
                    make_float2(score, __int_as_float(idx));
        }
    }
}

__global__ __launch_bounds__(64) void yolo_k2(
    const float* __restrict__ pred,
    const float* __restrict__ bboxes,
    const int*  __restrict__ classes,   // [B, G]
    const float2* __restrict__ partials,
    const float* __restrict__ bcepart,
    float* __restrict__ per_img)        // [B]
{
    const int b = blockIdx.x;
    const int g = threadIdx.x;

    float tot0 = 0.0f;
    #pragma unroll
    for (int s = 0; s < S; ++s) tot0 += bcepart[b * S + s];

    float per_gt = 0.0f;
    int   validf = 0;
    if (g < Gn) {
        int cls = classes[b * Gn + g];
        validf = (cls != -1) ? 1 : 0;

        // fold the S partial argmax candidates (scores comparable across splits)
        const float2* pp = partials + ((size_t)b * Gn + g) * S;
        float best = -1.0f;
        int   bidx = 0;
        #pragma unroll
        for (int s = 0; s < S; ++s) {
            float2 c = pp[s];
            if (c.x > best) { best = c.x; bidx = __float_as_int(c.y); }
        }

        const float* p = pred + ((size_t)b * An + bidx) * PRED_ROW;
        float pcx = p[0], pcy = p[1], pw = p[2], ph = p[3], conf = p[4];

        const float* bb = bboxes + ((size_t)b * Gn + g) * 4;
        float b0 = bb[0], b1 = bb[1], b2 = bb[2], b3 = bb[3];
        float gcx = 0.5f * (b0 + b2), gcy = 0.5f * (b1 + b3);
        float gw = b2 - b0, gh = b3 - b1;

        float dx = pcx - gcx, dy = pcy - gcy, dw = pw - gw, dh = ph - gh;
        float coord = LAMBDA_COORD * (dx * dx + dy * dy + dw * dw + dh * dh);

        float conf_obj = -fmaxf(__logf(conf), -100.0f);

        float clsl = 0.0f;
        #pragma unroll
        for (int c = 0; c < Cn; ++c) {
            float pc = p[5 + c];
            float lp = fmaxf(__logf(pc), -100.0f);
            float ln = fmaxf(__logf(1.0f - pc), -100.0f);
            clsl -= (c == cls) ? lp : ln;
        }

        float bce0b = -fmaxf(__logf(1.0f - conf), -100.0f);
        float noobj = LAMBDA_NOOBJ * (tot0 - bce0b);

        per_gt = coord + conf_obj + clsl + noobj;
        if (!validf) per_gt = 0.0f;
    }

    float sum = per_gt;
    int   anyv = validf;
    #pragma unroll
    for (int off = 1; off < 64; off <<= 1) {
        sum  += __shfl_xor(sum, off, 64);
        anyv |= __shfl_xor(anyv, off, 64);
    }
    if (g == 0) per_img[b] = anyv ? sum : (LAMBDA_NOOBJ * tot0);
}

__global__ __launch_bounds__(64) void yolo_k3(
    const float* __restrict__ per_img, float* __restrict__ out)
{
    float v = per_img[threadIdx.x];  // Bn == 64 == one wave
    #pragma unroll
    for (int off = 1; off < 64; off <<= 1) v += __shfl_xor(v, off, 64);
    if (threadIdx.x == 0) out[0] = v * (1.0f / (float)Bn);
}

extern "C" void kernel_launch(void* const* d_in, const int* in_sizes, int n_in,
                              void* d_out, int out_size, void* d_ws, size_t ws_size,
                              hipStream_t stream) {
    const float* pred    = (const float*)d_in[0];
    const float* bboxes  = (const float*)d_in[1];
    const int*   classes = (const int*)d_in[2];
    float* out = (float*)d_out;

    char* ws = (char*)d_ws;
    float2* partials = (float2*)ws;
    float*  bcepart  = (float*)(ws + (size_t)Bn * Gn * S * sizeof(float2));
    float*  per_img  = (float*)(ws + (size_t)Bn * Gn * S * sizeof(float2)
                                   + (size_t)Bn * S * sizeof(float));

    yolo_k1<<<dim3(S, Bn), 256, 0, stream>>>(pred, bboxes, partials, bcepart);
    yolo_k2<<<Bn, 64, 0, stream>>>(pred, bboxes, classes, partials, bcepart, per_img);
    yolo_k3<<<1, 64, 0, stream>>>(per_img, out);
}